// Round 2
// baseline (1746.467 us; speedup 1.0000x reference)
//
#include <hip/hip_runtime.h>

#define N_NODES 100000
#define N_EDGES 200000
#define IN_FEATS 1024
#define H_FEATS 512
#define N_HEADS 4
#define HEAD_DIM 128
#define N_CLASSES 2983
#define BATCH 1024

typedef __attribute__((ext_vector_type(8))) short short8;
typedef __attribute__((ext_vector_type(4))) float floatx4;

__device__ __forceinline__ float bf2f(unsigned short u) {
    union { unsigned int i; float f; } x; x.i = ((unsigned int)u) << 16; return x.f;
}
__device__ __forceinline__ unsigned short f2bf(float f) {
    union { float f; unsigned int i; } x; x.f = f;
    unsigned int r = x.i + 0x7FFFu + ((x.i >> 16) & 1u);
    return (unsigned short)(r >> 16);
}

// ---------------- GEMM ----------------
// C = A([M,K], fp32 or bf16) @ BT(bf16 [N,K])^T
// out_bf16 ? C bf16 : C fp32 (+bias). 128x128 tile, 4 waves, BK=32.
__global__ __launch_bounds__(256, 2)
void gemm_kernel(const void* __restrict__ Ain, const unsigned short* __restrict__ BT,
                 void* __restrict__ Cout, const float* __restrict__ bias,
                 int M, int N, int K, int a_bf16, int out_bf16)
{
    __shared__ unsigned short As[128 * 32];
    __shared__ unsigned short Bs[128 * 32];
    const int tid  = threadIdx.x;
    const int lane = tid & 63;
    const int wave = tid >> 6;
    const int m0 = blockIdx.x * 128;
    const int n0 = blockIdx.y * 128;
    const int wr = (wave >> 1) * 64;
    const int wc = (wave & 1) * 64;
    const int lm = lane & 15;
    const int quad = lane >> 4;

    floatx4 acc[4][4];
#pragma unroll
    for (int i = 0; i < 4; i++)
#pragma unroll
        for (int j = 0; j < 4; j++) acc[i][j] = (floatx4)0.0f;

    const int srow = tid >> 2;        // 0..63
    const int skc  = (tid & 3) * 8;   // 0,8,16,24

    for (int k0 = 0; k0 < K; k0 += 32) {
        __syncthreads();
        // stage A
#pragma unroll
        for (int p = 0; p < 2; p++) {
            int row = p * 64 + srow;
            int gr = m0 + row; if (gr > M - 1) gr = M - 1;
            short8 v;
            if (a_bf16) {
                v = *(const short8*)((const unsigned short*)Ain + (size_t)gr * K + k0 + skc);
            } else {
                const float* ap = (const float*)Ain + (size_t)gr * K + k0 + skc;
                floatx4 f0 = *(const floatx4*)ap;
                floatx4 f1 = *(const floatx4*)(ap + 4);
                v[0] = (short)f2bf(f0[0]); v[1] = (short)f2bf(f0[1]);
                v[2] = (short)f2bf(f0[2]); v[3] = (short)f2bf(f0[3]);
                v[4] = (short)f2bf(f1[0]); v[5] = (short)f2bf(f1[1]);
                v[6] = (short)f2bf(f1[2]); v[7] = (short)f2bf(f1[3]);
            }
            *(short8*)&As[row * 32 + skc] = v;
        }
        // stage B (bf16 [N,K] row-major)
#pragma unroll
        for (int p = 0; p < 2; p++) {
            int row = p * 64 + srow;
            int gn = n0 + row; if (gn > N - 1) gn = N - 1;
            const unsigned short* bp = BT + (size_t)gn * K + k0 + skc;
            *(short8*)&Bs[row * 32 + skc] = *(const short8*)bp;
        }
        __syncthreads();
        short8 af[4], bfr[4];
#pragma unroll
        for (int i = 0; i < 4; i++)
            af[i] = *(const short8*)&As[(wr + i * 16 + lm) * 32 + quad * 8];
#pragma unroll
        for (int j = 0; j < 4; j++)
            bfr[j] = *(const short8*)&Bs[(wc + j * 16 + lm) * 32 + quad * 8];
#pragma unroll
        for (int i = 0; i < 4; i++)
#pragma unroll
            for (int j = 0; j < 4; j++)
                acc[i][j] = __builtin_amdgcn_mfma_f32_16x16x32_bf16(af[i], bfr[j], acc[i][j], 0, 0, 0);
    }

    // epilogue: C/D layout col=lane&15, row=quad*4+reg
#pragma unroll
    for (int i = 0; i < 4; i++) {
        int grb = m0 + wr + i * 16 + quad * 4;
#pragma unroll
        for (int j = 0; j < 4; j++) {
            int gc = n0 + wc + j * 16 + lm;
            if (gc < N) {
#pragma unroll
                for (int r = 0; r < 4; r++) {
                    int gr = grb + r;
                    if (gr < M) {
                        float v = acc[i][j][r];
                        if (out_bf16) {
                            ((unsigned short*)Cout)[(size_t)gr * N + gc] = f2bf(v);
                        } else {
                            float b = bias ? bias[gc] : 0.0f;
                            ((float*)Cout)[(size_t)gr * N + gc] = v + b;
                        }
                    }
                }
            }
        }
    }
}

// ---------------- attention logits ----------------
__global__ void alpha_kernel(const unsigned short* __restrict__ H,
                             const float* __restrict__ a_s, const float* __restrict__ a_d,
                             float* __restrict__ asrc, float* __restrict__ adst, int Nn)
{
    int node = blockIdx.x * 4 + (threadIdx.x >> 6);
    if (node >= Nn) return;
    int lane = threadIdx.x & 63;
    int col = lane * 8;
    const unsigned short* hp = H + (size_t)node * 512 + col;
    short8 hv = *(const short8*)hp;
    float ss = 0.f, sd = 0.f;
#pragma unroll
    for (int j = 0; j < 8; j++) {
        float v = bf2f((unsigned short)hv[j]);
        ss += v * a_s[col + j];
        sd += v * a_d[col + j];
    }
#pragma unroll
    for (int off = 1; off < 16; off <<= 1) {
        ss += __shfl_xor(ss, off);
        sd += __shfl_xor(sd, off);
    }
    if ((lane & 15) == 0) {
        asrc[node * 4 + (lane >> 4)] = ss;
        adst[node * 4 + (lane >> 4)] = sd;
    }
}

// ---------------- CSR build ----------------
__global__ void hist_kernel(const int* __restrict__ dst, int* __restrict__ cnt, int E)
{
    int e = blockIdx.x * blockDim.x + threadIdx.x;
    if (e < E) atomicAdd(&cnt[dst[e]], 1);
}

__global__ void scan1_kernel(const int* __restrict__ cnt, int* __restrict__ partial,
                             int* __restrict__ chunksum, int n)
{
    __shared__ int sm[256];
    int t = threadIdx.x;
    int i = blockIdx.x * 256 + t;
    int v = (i < n) ? cnt[i] : 0;
    sm[t] = v; __syncthreads();
    int val = v;
#pragma unroll
    for (int off = 1; off < 256; off <<= 1) {
        int u = (t >= off) ? sm[t - off] : 0;
        __syncthreads();
        val += u; sm[t] = val;
        __syncthreads();
    }
    if (i < n) partial[i] = val - v;          // exclusive within chunk
    if (t == 255) chunksum[blockIdx.x] = val; // chunk total
}

__global__ void scan2_kernel(int* __restrict__ chunksum, int n)
{
    __shared__ int sm[512];
    int t = threadIdx.x;
    int v = (t < n) ? chunksum[t] : 0;
    sm[t] = v; __syncthreads();
    int val = v;
#pragma unroll
    for (int off = 1; off < 512; off <<= 1) {
        int u = (t >= off) ? sm[t - off] : 0;
        __syncthreads();
        val += u; sm[t] = val;
        __syncthreads();
    }
    if (t < n) chunksum[t] = val - v;         // exclusive over chunks
}

__global__ void scan3_kernel(const int* __restrict__ partial, const int* __restrict__ chunksum,
                             int* __restrict__ rowptr, int* __restrict__ cursor, int n, int E)
{
    int i = blockIdx.x * 256 + threadIdx.x;
    if (i < n) {
        int r = partial[i] + chunksum[i >> 8];
        rowptr[i] = r;
        cursor[i] = r;
    }
    if (i == 0) rowptr[n] = E;
}

__global__ void fill_kernel(const int* __restrict__ src, const int* __restrict__ dst,
                            int* __restrict__ cursor, int* __restrict__ srcs_sorted, int E)
{
    int e = blockIdx.x * blockDim.x + threadIdx.x;
    if (e < E) {
        int p = atomicAdd(&cursor[dst[e]], 1);
        srcs_sorted[p] = src[e];
    }
}

// ---------------- CSR gather (softmax + weighted sum fused) ----------------
// one wave per dst node; lane owns 8 contiguous feature cols (head = lane>>4)
__global__ void gather_kernel(const int* __restrict__ rowptr, const int* __restrict__ srcs,
                              const float* __restrict__ asrc, const float* __restrict__ adst,
                              const unsigned short* __restrict__ H,
                              unsigned short* __restrict__ OutBf, int ndst, int add)
{
    int d = blockIdx.x * 4 + (threadIdx.x >> 6);
    if (d >= ndst) return;
    int lane = threadIdx.x & 63;
    int head = lane >> 4;
    int col = lane * 8;
    int beg = rowptr[d], end = rowptr[d + 1];
    float ad = adst[d * 4 + head];
    float acc[8];
#pragma unroll
    for (int k = 0; k < 8; k++) acc[k] = 0.f;
    float den = 0.f;
    for (int j = beg; j < end; j++) {
        int s = srcs[j];
        float v = asrc[s * 4 + head] + ad;
        v = v > 0.f ? v : 0.2f * v;
        float ex = expf(v);
        den += ex;
        short8 hv = *(const short8*)(H + (size_t)s * 512 + col);
#pragma unroll
        for (int k = 0; k < 8; k++) acc[k] += ex * bf2f((unsigned short)hv[k]);
    }
    float inv = den > 0.f ? 1.f / den : 0.f;
    unsigned short* op = OutBf + (size_t)d * 512 + col;
    short8 out;
    if (add) {
        short8 old = *(const short8*)op;
#pragma unroll
        for (int k = 0; k < 8; k++) out[k] = (short)f2bf(bf2f((unsigned short)old[k]) + acc[k] * inv);
    } else {
#pragma unroll
        for (int k = 0; k < 8; k++) out[k] = (short)f2bf(acc[k] * inv);
    }
    *(short8*)op = out;
}

// in-place: A = lrelu(A + b1 + b2, 0.01) over bf16 [Nn,512]
__global__ void combine_lrelu_kernel(unsigned short* __restrict__ A, const float* __restrict__ b1,
                                     const float* __restrict__ b2, int Nn)
{
    int idx = blockIdx.x * blockDim.x + threadIdx.x;
    if (idx >= Nn * 64) return;
    int colb = (idx & 63) * 8;
    unsigned short* p = A + (size_t)idx * 8;
    short8 v = *(const short8*)p;
    short8 o;
#pragma unroll
    for (int k = 0; k < 8; k++) {
        float f = bf2f((unsigned short)v[k]) + b1[colb + k] + b2[colb + k];
        f = f > 0.f ? f : 0.01f * f;
        o[k] = (short)f2bf(f);
    }
    *(short8*)p = o;
}

// h2s(bf16) = Acc2(bf16) + b1 + b2, rows x 512
__global__ void h2prep_kernel(const unsigned short* __restrict__ Acc2, const float* __restrict__ b1,
                              const float* __restrict__ b2, unsigned short* __restrict__ h2s, int rows)
{
    int idx = blockIdx.x * blockDim.x + threadIdx.x;
    if (idx >= rows * 64) return;
    int colb = (idx & 63) * 8;
    short8 v = *(const short8*)(Acc2 + (size_t)idx * 8);
    short8 o;
#pragma unroll
    for (int k = 0; k < 8; k++)
        o[k] = (short)f2bf(bf2f((unsigned short)v[k]) + b1[colb + k] + b2[colb + k]);
    *(short8*)(h2s + (size_t)idx * 8) = o;
}

// W[K][N] fp32 -> WT[N][K] bf16
__global__ void transpose_conv_kernel(const float* __restrict__ W, unsigned short* __restrict__ WT,
                                      int K, int N)
{
    int idx = blockIdx.x * blockDim.x + threadIdx.x;
    if (idx >= K * N) return;
    int n = idx / K, k = idx - n * K;
    WT[idx] = f2bf(W[(size_t)k * N + n]);
}

extern "C" void kernel_launch(void* const* d_in, const int* in_sizes, int n_in,
                              void* d_out, int out_size, void* d_ws, size_t ws_size,
                              hipStream_t stream)
{
    const float* x    = (const float*)d_in[0];
    const int* e1s    = (const int*)d_in[1];
    const int* e1d    = (const int*)d_in[2];
    const int* e2s    = (const int*)d_in[3];
    const int* e2d    = (const int*)d_in[4];
    const float* w0a  = (const float*)d_in[6];
    const float* as0a = (const float*)d_in[7];
    const float* ad0a = (const float*)d_in[8];
    const float* b0a  = (const float*)d_in[9];
    const float* w0b  = (const float*)d_in[10];
    const float* as0b = (const float*)d_in[11];
    const float* ad0b = (const float*)d_in[12];
    const float* b0b  = (const float*)d_in[13];
    const float* w1a  = (const float*)d_in[14];
    const float* as1a = (const float*)d_in[15];
    const float* ad1a = (const float*)d_in[16];
    const float* b1a  = (const float*)d_in[17];
    const float* w1b  = (const float*)d_in[18];
    const float* as1b = (const float*)d_in[19];
    const float* ad1b = (const float*)d_in[20];
    const float* b1b  = (const float*)d_in[21];
    const float* linw = (const float*)d_in[22];
    const float* linb = (const float*)d_in[23];
    float* out = (float*)d_out;
    (void)in_sizes; (void)n_in; (void)out_size; (void)ws_size;

    char* ws = (char*)d_ws;
    size_t off = 0;
    auto carve = [&](size_t bytes) -> void* {
        void* p = ws + off; off += (bytes + 255) & ~(size_t)255; return p;
    };
    // weights (bf16 [N,K])
    unsigned short* WT0a = (unsigned short*)carve((size_t)H_FEATS * IN_FEATS * 2);
    unsigned short* WT0b = (unsigned short*)carve((size_t)H_FEATS * IN_FEATS * 2);
    unsigned short* WT1a = (unsigned short*)carve((size_t)H_FEATS * H_FEATS * 2);
    unsigned short* WT1b = (unsigned short*)carve((size_t)H_FEATS * H_FEATS * 2);
    unsigned short* WTl  = (unsigned short*)carve((size_t)N_CLASSES * H_FEATS * 2);
    // features
    unsigned short* Hbf  = (unsigned short*)carve((size_t)N_NODES * H_FEATS * 2);  // per-conv H
    unsigned short* H1   = (unsigned short*)carve((size_t)N_NODES * H_FEATS * 2);  // layer-0 out
    unsigned short* Acc2 = (unsigned short*)carve((size_t)BATCH * H_FEATS * 2);    // layer-1 out (seeds)
    unsigned short* h2s  = (unsigned short*)carve((size_t)BATCH * H_FEATS * 2);
    // attention scalars
    float* asrc = (float*)carve((size_t)N_NODES * N_HEADS * 4);
    float* adst = (float*)carve((size_t)N_NODES * N_HEADS * 4);
    // CSR
    int* rowptr1 = (int*)carve((size_t)(N_NODES + 1) * 4);
    int* rowptr2 = (int*)carve((size_t)(N_NODES + 1) * 4);
    int* srcs1   = (int*)carve((size_t)N_EDGES * 4);
    int* srcs2   = (int*)carve((size_t)N_EDGES * 4);
    int* cnt     = (int*)carve((size_t)N_NODES * 4);
    int* partial = (int*)carve((size_t)N_NODES * 4);
    int* chunksum= (int*)carve((size_t)512 * 4);

    const int NCHUNK = (N_NODES + 255) / 256;   // 391

    // --- weight transposes ---
    {
        int t0 = IN_FEATS * H_FEATS;
        transpose_conv_kernel<<<(t0 + 255) / 256, 256, 0, stream>>>(w0a, WT0a, IN_FEATS, H_FEATS);
        transpose_conv_kernel<<<(t0 + 255) / 256, 256, 0, stream>>>(w0b, WT0b, IN_FEATS, H_FEATS);
        int t1 = H_FEATS * H_FEATS;
        transpose_conv_kernel<<<(t1 + 255) / 256, 256, 0, stream>>>(w1a, WT1a, H_FEATS, H_FEATS);
        transpose_conv_kernel<<<(t1 + 255) / 256, 256, 0, stream>>>(w1b, WT1b, H_FEATS, H_FEATS);
        int t2 = H_FEATS * N_CLASSES;
        transpose_conv_kernel<<<(t2 + 255) / 256, 256, 0, stream>>>(linw, WTl, H_FEATS, N_CLASSES);
    }

    // --- CSR build for both edge types ---
    auto build_csr = [&](const int* src, const int* dst, int* rowptr, int* srcs_sorted) {
        hipMemsetAsync(cnt, 0, (size_t)N_NODES * 4, stream);
        hist_kernel<<<(N_EDGES + 255) / 256, 256, 0, stream>>>(dst, cnt, N_EDGES);
        scan1_kernel<<<NCHUNK, 256, 0, stream>>>(cnt, partial, chunksum, N_NODES);
        scan2_kernel<<<1, 512, 0, stream>>>(chunksum, NCHUNK);
        scan3_kernel<<<NCHUNK, 256, 0, stream>>>(partial, chunksum, rowptr, cnt, N_NODES, N_EDGES);
        fill_kernel<<<(N_EDGES + 255) / 256, 256, 0, stream>>>(src, dst, cnt, srcs_sorted, N_EDGES);
    };
    build_csr(e1s, e1d, rowptr1, srcs1);
    build_csr(e2s, e2d, rowptr2, srcs2);

    // --- one GATConv ---
    auto run_conv = [&](const void* Ain, int a_bf16, int Kdim, const unsigned short* WT,
                        const float* avs, const float* avd,
                        const int* rowptr, const int* srcs,
                        unsigned short* OutBf, int ndst, int add) {
        dim3 gg((N_NODES + 127) / 128, (H_FEATS + 127) / 128);
        gemm_kernel<<<gg, 256, 0, stream>>>(Ain, WT, Hbf, nullptr, N_NODES, H_FEATS, Kdim, a_bf16, 1);
        alpha_kernel<<<(N_NODES + 3) / 4, 256, 0, stream>>>(Hbf, avs, avd, asrc, adst, N_NODES);
        gather_kernel<<<(ndst + 3) / 4, 256, 0, stream>>>(rowptr, srcs, asrc, adst, Hbf, OutBf, ndst, add);
    };

    // layer 0: both convs -> H1 (bf16), then +biases, lrelu in place
    run_conv(x, 0, IN_FEATS, WT0a, as0a, ad0a, rowptr1, srcs1, H1, N_NODES, 0);
    run_conv(x, 0, IN_FEATS, WT0b, as0b, ad0b, rowptr2, srcs2, H1, N_NODES, 1);
    combine_lrelu_kernel<<<(N_NODES * 64 + 255) / 256, 256, 0, stream>>>(H1, b0a, b0b, N_NODES);

    // layer 1: only seed nodes (dst < BATCH) are needed downstream
    run_conv(H1, 1, H_FEATS, WT1a, as1a, ad1a, rowptr1, srcs1, Acc2, BATCH, 0);
    run_conv(H1, 1, H_FEATS, WT1b, as1b, ad1b, rowptr2, srcs2, Acc2, BATCH, 1);

    // head
    h2prep_kernel<<<(BATCH * 64 + 255) / 256, 256, 0, stream>>>(Acc2, b1a, b1b, h2s, BATCH);
    dim3 gh((BATCH + 127) / 128, (N_CLASSES + 127) / 128);
    gemm_kernel<<<gh, 256, 0, stream>>>(h2s, WTl, out, linb, BATCH, N_CLASSES, H_FEATS, 1, 0);
}

// Round 3
// 1613.841 us; speedup vs baseline: 1.0822x; 1.0822x over previous
//
#include <hip/hip_runtime.h>

#define N_NODES 100000
#define N_EDGES 200000
#define IN_FEATS 1024
#define H_FEATS 512
#define N_HEADS 4
#define HEAD_DIM 128
#define N_CLASSES 2983
#define BATCH 1024

typedef __attribute__((ext_vector_type(8))) short short8;
typedef __attribute__((ext_vector_type(4))) float floatx4;

typedef __attribute__((address_space(1))) void global_as_void;
typedef __attribute__((address_space(3))) void lds_as_void;

__device__ __forceinline__ float bf2f(unsigned short u) {
    union { unsigned int i; float f; } x; x.i = ((unsigned int)u) << 16; return x.f;
}
__device__ __forceinline__ unsigned short f2bf(float f) {
    union { float f; unsigned int i; } x; x.f = f;
    unsigned int r = x.i + 0x7FFFu + ((x.i >> 16) & 1u);
    return (unsigned short)(r >> 16);
}
__device__ __forceinline__ void load_lds16(const void* g, void* l) {
    __builtin_amdgcn_global_load_lds((const global_as_void*)g, (lds_as_void*)l, 16, 0, 0);
}

// ---------------- GEMM ----------------
// C[M,N] = A([M,K] bf16, or fp32 if a_fp32) @ BT(bf16 [N,K])^T
// out_bf16 ? C bf16 : C fp32 (+bias).
// If att_s != null (GAT conv, N==512): each 128-col tile is one head; the
// epilogue also computes asrc/adst row logits via shfl-reduce + atomicAdd.
// LDS layout swizzle: 16B slot c of row r holds global k-chunk c ^ ((r>>1)&3).
__global__ __launch_bounds__(256, 3)
void gemm_kernel(const void* __restrict__ Ain, int a_fp32,
                 const unsigned short* __restrict__ BT,
                 void* __restrict__ Cout, const float* __restrict__ bias,
                 const float* __restrict__ att_s, const float* __restrict__ att_d,
                 float* __restrict__ asrc, float* __restrict__ adst,
                 int M, int N, int K, int out_bf16)
{
    __shared__ __attribute__((aligned(16))) unsigned short As[128 * 32];
    __shared__ __attribute__((aligned(16))) unsigned short Bs[128 * 32];
    const int tid  = threadIdx.x;
    const int lane = tid & 63;
    const int wave = tid >> 6;
    const int m0 = blockIdx.x * 128;
    const int n0 = blockIdx.y * 128;
    const int wr = (wave >> 1) * 64;
    const int wc = (wave & 1) * 64;
    const int lm = lane & 15;
    const int quad = lane >> 4;

    floatx4 acc[4][4];
#pragma unroll
    for (int i = 0; i < 4; i++)
#pragma unroll
        for (int j = 0; j < 4; j++) acc[i][j] = (floatx4)0.0f;

    for (int k0 = 0; k0 < K; k0 += 32) {
        __syncthreads();
        if (a_fp32) {
            // VALU staging: fp32 -> bf16, same swizzled layout
            int row = tid >> 2;
            int slot = tid & 3;
#pragma unroll
            for (int p = 0; p < 2; p++) {
                int r = p * 64 + row;
                int gr = m0 + r; if (gr > M - 1) gr = M - 1;
                int gc = (slot ^ ((r >> 1) & 3)) * 8;
                const float* ap = (const float*)Ain + (size_t)gr * K + k0 + gc;
                floatx4 f0 = *(const floatx4*)ap;
                floatx4 f1 = *(const floatx4*)(ap + 4);
                short8 v;
                v[0] = (short)f2bf(f0[0]); v[1] = (short)f2bf(f0[1]);
                v[2] = (short)f2bf(f0[2]); v[3] = (short)f2bf(f0[3]);
                v[4] = (short)f2bf(f1[0]); v[5] = (short)f2bf(f1[1]);
                v[6] = (short)f2bf(f1[2]); v[7] = (short)f2bf(f1[3]);
                *(short8*)&As[r * 32 + slot * 8] = v;
            }
        } else {
            // direct global->LDS DMA, 16B/lane; dest = wave-uniform base + lane*16
#pragma unroll
            for (int i = 0; i < 2; i++) {
                int r = wave * 32 + i * 16 + (lane >> 2);
                int gr = m0 + r; if (gr > M - 1) gr = M - 1;
                int gc = ((lane & 3) ^ ((r >> 1) & 3)) * 8;
                load_lds16((const unsigned short*)Ain + (size_t)gr * K + k0 + gc,
                           (char*)As + (size_t)(wave * 2 + i) * 1024);
            }
        }
#pragma unroll
        for (int i = 0; i < 2; i++) {
            int r = wave * 32 + i * 16 + (lane >> 2);
            int gn = n0 + r; if (gn > N - 1) gn = N - 1;
            int gc = ((lane & 3) ^ ((r >> 1) & 3)) * 8;
            load_lds16(BT + (size_t)gn * K + k0 + gc,
                       (char*)Bs + (size_t)(wave * 2 + i) * 1024);
        }
        __syncthreads();
        short8 af[4], bfr[4];
#pragma unroll
        for (int i = 0; i < 4; i++) {
            int ra = wr + i * 16 + lm;
            af[i] = *(const short8*)&As[ra * 32 + ((quad ^ ((ra >> 1) & 3)) << 3)];
            int rb = wc + i * 16 + lm;
            bfr[i] = *(const short8*)&Bs[rb * 32 + ((quad ^ ((rb >> 1) & 3)) << 3)];
        }
#pragma unroll
        for (int i = 0; i < 4; i++)
#pragma unroll
            for (int j = 0; j < 4; j++)
                acc[i][j] = __builtin_amdgcn_mfma_f32_16x16x32_bf16(af[i], bfr[j], acc[i][j], 0, 0, 0);
    }

    // fused attention logits (per row of this head's 128 cols)
    if (att_s) {
        const int h = n0 >> 7;
#pragma unroll
        for (int i = 0; i < 4; i++) {
#pragma unroll
            for (int r = 0; r < 4; r++) {
                float ss = 0.f, sd = 0.f;
#pragma unroll
                for (int j = 0; j < 4; j++) {
                    int c = wc + j * 16 + lm;
                    ss += acc[i][j][r] * att_s[h * HEAD_DIM + c];
                    sd += acc[i][j][r] * att_d[h * HEAD_DIM + c];
                }
#pragma unroll
                for (int off = 1; off < 16; off <<= 1) {
                    ss += __shfl_xor(ss, off);
                    sd += __shfl_xor(sd, off);
                }
                int gr = m0 + wr + i * 16 + quad * 4 + r;
                if (lm == 0 && gr < M) {
                    atomicAdd(&asrc[(size_t)gr * 4 + h], ss);
                    atomicAdd(&adst[(size_t)gr * 4 + h], sd);
                }
            }
        }
    }

    // C store: C/D layout col=lane&15, row=quad*4+reg
#pragma unroll
    for (int i = 0; i < 4; i++) {
        int grb = m0 + wr + i * 16 + quad * 4;
#pragma unroll
        for (int j = 0; j < 4; j++) {
            int gc = n0 + wc + j * 16 + lm;
            if (gc < N) {
#pragma unroll
                for (int r = 0; r < 4; r++) {
                    int gr = grb + r;
                    if (gr < M) {
                        float v = acc[i][j][r];
                        if (out_bf16) {
                            ((unsigned short*)Cout)[(size_t)gr * N + gc] = f2bf(v);
                        } else {
                            float b = bias ? bias[gc] : 0.0f;
                            ((float*)Cout)[(size_t)gr * N + gc] = v + b;
                        }
                    }
                }
            }
        }
    }
}

// ---------------- fp32 -> bf16 bulk convert ----------------
__global__ void cvt_bf16_kernel(const float* __restrict__ X, unsigned short* __restrict__ Y, int n8)
{
    int i = blockIdx.x * blockDim.x + threadIdx.x;
    if (i >= n8) return;
    const floatx4* xp = (const floatx4*)X + (size_t)i * 2;
    floatx4 f0 = xp[0], f1 = xp[1];
    short8 v;
    v[0] = (short)f2bf(f0[0]); v[1] = (short)f2bf(f0[1]);
    v[2] = (short)f2bf(f0[2]); v[3] = (short)f2bf(f0[3]);
    v[4] = (short)f2bf(f1[0]); v[5] = (short)f2bf(f1[1]);
    v[6] = (short)f2bf(f1[2]); v[7] = (short)f2bf(f1[3]);
    *(short8*)(Y + (size_t)i * 8) = v;
}

// ---------------- CSR build ----------------
__global__ void hist_kernel(const int* __restrict__ dst, int* __restrict__ cnt, int E)
{
    int e = blockIdx.x * blockDim.x + threadIdx.x;
    if (e < E) atomicAdd(&cnt[dst[e]], 1);
}

__global__ void scan1_kernel(const int* __restrict__ cnt, int* __restrict__ partial,
                             int* __restrict__ chunksum, int n)
{
    __shared__ int sm[256];
    int t = threadIdx.x;
    int i = blockIdx.x * 256 + t;
    int v = (i < n) ? cnt[i] : 0;
    sm[t] = v; __syncthreads();
    int val = v;
#pragma unroll
    for (int off = 1; off < 256; off <<= 1) {
        int u = (t >= off) ? sm[t - off] : 0;
        __syncthreads();
        val += u; sm[t] = val;
        __syncthreads();
    }
    if (i < n) partial[i] = val - v;
    if (t == 255) chunksum[blockIdx.x] = val;
}

__global__ void scan2_kernel(int* __restrict__ chunksum, int n)
{
    __shared__ int sm[512];
    int t = threadIdx.x;
    int v = (t < n) ? chunksum[t] : 0;
    sm[t] = v; __syncthreads();
    int val = v;
#pragma unroll
    for (int off = 1; off < 512; off <<= 1) {
        int u = (t >= off) ? sm[t - off] : 0;
        __syncthreads();
        val += u; sm[t] = val;
        __syncthreads();
    }
    if (t < n) chunksum[t] = val - v;
}

__global__ void scan3_kernel(const int* __restrict__ partial, const int* __restrict__ chunksum,
                             int* __restrict__ rowptr, int* __restrict__ cursor, int n, int E)
{
    int i = blockIdx.x * 256 + threadIdx.x;
    if (i < n) {
        int r = partial[i] + chunksum[i >> 8];
        rowptr[i] = r;
        cursor[i] = r;
    }
    if (i == 0) rowptr[n] = E;
}

__global__ void fill_kernel(const int* __restrict__ src, const int* __restrict__ dst,
                            int* __restrict__ cursor, int* __restrict__ srcs_sorted, int E)
{
    int e = blockIdx.x * blockDim.x + threadIdx.x;
    if (e < E) {
        int p = atomicAdd(&cursor[dst[e]], 1);
        srcs_sorted[p] = src[e];
    }
}

// ---------------- CSR gather (softmax + weighted sum fused) ----------------
__global__ void gather_kernel(const int* __restrict__ rowptr, const int* __restrict__ srcs,
                              const float* __restrict__ asrc, const float* __restrict__ adst,
                              const unsigned short* __restrict__ H,
                              unsigned short* __restrict__ OutBf, int ndst, int add)
{
    int d = blockIdx.x * 4 + (threadIdx.x >> 6);
    if (d >= ndst) return;
    int lane = threadIdx.x & 63;
    int head = lane >> 4;
    int col = lane * 8;
    int beg = rowptr[d], end = rowptr[d + 1];
    float ad = adst[d * 4 + head];
    float acc[8];
#pragma unroll
    for (int k = 0; k < 8; k++) acc[k] = 0.f;
    float den = 0.f;
    for (int j = beg; j < end; j++) {
        int s = srcs[j];
        float v = asrc[s * 4 + head] + ad;
        v = v > 0.f ? v : 0.2f * v;
        float ex = expf(v);
        den += ex;
        short8 hv = *(const short8*)(H + (size_t)s * 512 + col);
#pragma unroll
        for (int k = 0; k < 8; k++) acc[k] += ex * bf2f((unsigned short)hv[k]);
    }
    float inv = den > 0.f ? 1.f / den : 0.f;
    unsigned short* op = OutBf + (size_t)d * 512 + col;
    short8 out;
    if (add) {
        short8 old = *(const short8*)op;
#pragma unroll
        for (int k = 0; k < 8; k++) out[k] = (short)f2bf(bf2f((unsigned short)old[k]) + acc[k] * inv);
    } else {
#pragma unroll
        for (int k = 0; k < 8; k++) out[k] = (short)f2bf(acc[k] * inv);
    }
    *(short8*)op = out;
}

// in-place: A = lrelu(A + b1 + b2, 0.01) over bf16 [Nn,512]
__global__ void combine_lrelu_kernel(unsigned short* __restrict__ A, const float* __restrict__ b1,
                                     const float* __restrict__ b2, int Nn)
{
    int idx = blockIdx.x * blockDim.x + threadIdx.x;
    if (idx >= Nn * 64) return;
    int colb = (idx & 63) * 8;
    unsigned short* p = A + (size_t)idx * 8;
    short8 v = *(const short8*)p;
    short8 o;
#pragma unroll
    for (int k = 0; k < 8; k++) {
        float f = bf2f((unsigned short)v[k]) + b1[colb + k] + b2[colb + k];
        f = f > 0.f ? f : 0.01f * f;
        o[k] = (short)f2bf(f);
    }
    *(short8*)p = o;
}

// h2s(bf16) = Acc2(bf16) + b1 + b2, rows x 512
__global__ void h2prep_kernel(const unsigned short* __restrict__ Acc2, const float* __restrict__ b1,
                              const float* __restrict__ b2, unsigned short* __restrict__ h2s, int rows)
{
    int idx = blockIdx.x * blockDim.x + threadIdx.x;
    if (idx >= rows * 64) return;
    int colb = (idx & 63) * 8;
    short8 v = *(const short8*)(Acc2 + (size_t)idx * 8);
    short8 o;
#pragma unroll
    for (int k = 0; k < 8; k++)
        o[k] = (short)f2bf(bf2f((unsigned short)v[k]) + b1[colb + k] + b2[colb + k]);
    *(short8*)(h2s + (size_t)idx * 8) = o;
}

// W[K][N] fp32 -> WT[N][K] bf16
__global__ void transpose_conv_kernel(const float* __restrict__ W, unsigned short* __restrict__ WT,
                                      int K, int N)
{
    int idx = blockIdx.x * blockDim.x + threadIdx.x;
    if (idx >= K * N) return;
    int n = idx / K, k = idx - n * K;
    WT[idx] = f2bf(W[(size_t)k * N + n]);
}

extern "C" void kernel_launch(void* const* d_in, const int* in_sizes, int n_in,
                              void* d_out, int out_size, void* d_ws, size_t ws_size,
                              hipStream_t stream)
{
    const float* x    = (const float*)d_in[0];
    const int* e1s    = (const int*)d_in[1];
    const int* e1d    = (const int*)d_in[2];
    const int* e2s    = (const int*)d_in[3];
    const int* e2d    = (const int*)d_in[4];
    const float* w0a  = (const float*)d_in[6];
    const float* as0a = (const float*)d_in[7];
    const float* ad0a = (const float*)d_in[8];
    const float* b0a  = (const float*)d_in[9];
    const float* w0b  = (const float*)d_in[10];
    const float* as0b = (const float*)d_in[11];
    const float* ad0b = (const float*)d_in[12];
    const float* b0b  = (const float*)d_in[13];
    const float* w1a  = (const float*)d_in[14];
    const float* as1a = (const float*)d_in[15];
    const float* ad1a = (const float*)d_in[16];
    const float* b1a  = (const float*)d_in[17];
    const float* w1b  = (const float*)d_in[18];
    const float* as1b = (const float*)d_in[19];
    const float* ad1b = (const float*)d_in[20];
    const float* b1b  = (const float*)d_in[21];
    const float* linw = (const float*)d_in[22];
    const float* linb = (const float*)d_in[23];
    float* out = (float*)d_out;
    (void)in_sizes; (void)n_in; (void)out_size;

    char* ws = (char*)d_ws;
    size_t off = 0;
    auto carve = [&](size_t bytes) -> void* {
        void* p = ws + off; off += (bytes + 255) & ~(size_t)255; return p;
    };
    unsigned short* WT0a = (unsigned short*)carve((size_t)H_FEATS * IN_FEATS * 2);
    unsigned short* WT0b = (unsigned short*)carve((size_t)H_FEATS * IN_FEATS * 2);
    unsigned short* WT1a = (unsigned short*)carve((size_t)H_FEATS * H_FEATS * 2);
    unsigned short* WT1b = (unsigned short*)carve((size_t)H_FEATS * H_FEATS * 2);
    unsigned short* WTl  = (unsigned short*)carve((size_t)N_CLASSES * H_FEATS * 2);
    unsigned short* Hbf  = (unsigned short*)carve((size_t)N_NODES * H_FEATS * 2);
    unsigned short* H1   = (unsigned short*)carve((size_t)N_NODES * H_FEATS * 2);
    unsigned short* Acc2 = (unsigned short*)carve((size_t)BATCH * H_FEATS * 2);
    unsigned short* h2s  = (unsigned short*)carve((size_t)BATCH * H_FEATS * 2);
    float* asrc = (float*)carve((size_t)N_NODES * N_HEADS * 4);
    float* adst = (float*)carve((size_t)N_NODES * N_HEADS * 4);
    int* rowptr1 = (int*)carve((size_t)(N_NODES + 1) * 4);
    int* rowptr2 = (int*)carve((size_t)(N_NODES + 1) * 4);
    int* srcs1   = (int*)carve((size_t)N_EDGES * 4);
    int* srcs2   = (int*)carve((size_t)N_EDGES * 4);
    int* cnt     = (int*)carve((size_t)N_NODES * 4);
    int* partial = (int*)carve((size_t)N_NODES * 4);
    int* chunksum= (int*)carve((size_t)512 * 4);
    // x-as-bf16 is large (205 MB): only use it if the workspace is big enough.
    // Decision depends only on ws_size -> identical on every call (capture-safe).
    unsigned short* xbf = nullptr;
    {
        size_t need = (size_t)N_NODES * IN_FEATS * 2;
        if (off + need <= ws_size) xbf = (unsigned short*)carve(need);
    }

    const int NCHUNK = (N_NODES + 255) / 256;   // 391

    // --- weight transposes ---
    {
        int t0 = IN_FEATS * H_FEATS;
        transpose_conv_kernel<<<(t0 + 255) / 256, 256, 0, stream>>>(w0a, WT0a, IN_FEATS, H_FEATS);
        transpose_conv_kernel<<<(t0 + 255) / 256, 256, 0, stream>>>(w0b, WT0b, IN_FEATS, H_FEATS);
        int t1 = H_FEATS * H_FEATS;
        transpose_conv_kernel<<<(t1 + 255) / 256, 256, 0, stream>>>(w1a, WT1a, H_FEATS, H_FEATS);
        transpose_conv_kernel<<<(t1 + 255) / 256, 256, 0, stream>>>(w1b, WT1b, H_FEATS, H_FEATS);
        int t2 = H_FEATS * N_CLASSES;
        transpose_conv_kernel<<<(t2 + 255) / 256, 256, 0, stream>>>(linw, WTl, H_FEATS, N_CLASSES);
    }

    // --- x -> bf16 (if workspace allows) ---
    if (xbf) {
        int n8 = N_NODES * IN_FEATS / 8;
        cvt_bf16_kernel<<<(n8 + 255) / 256, 256, 0, stream>>>(x, xbf, n8);
    }

    // --- CSR build for both edge types ---
    auto build_csr = [&](const int* src, const int* dst, int* rowptr, int* srcs_sorted) {
        hipMemsetAsync(cnt, 0, (size_t)N_NODES * 4, stream);
        hist_kernel<<<(N_EDGES + 255) / 256, 256, 0, stream>>>(dst, cnt, N_EDGES);
        scan1_kernel<<<NCHUNK, 256, 0, stream>>>(cnt, partial, chunksum, N_NODES);
        scan2_kernel<<<1, 512, 0, stream>>>(chunksum, NCHUNK);
        scan3_kernel<<<NCHUNK, 256, 0, stream>>>(partial, chunksum, rowptr, cnt, N_NODES, N_EDGES);
        fill_kernel<<<(N_EDGES + 255) / 256, 256, 0, stream>>>(src, dst, cnt, srcs_sorted, N_EDGES);
    };
    build_csr(e1s, e1d, rowptr1, srcs1);
    build_csr(e2s, e2d, rowptr2, srcs2);

    // --- one GATConv: GEMM (+fused alpha) -> gather ---
    auto run_conv = [&](const void* Ain, int a_fp32, int Kdim, const unsigned short* WT,
                        const float* avs, const float* avd,
                        const int* rowptr, const int* srcs,
                        unsigned short* OutBf, int ndst, int add) {
        hipMemsetAsync(asrc, 0, (size_t)N_NODES * N_HEADS * 4, stream);
        hipMemsetAsync(adst, 0, (size_t)N_NODES * N_HEADS * 4, stream);
        dim3 gg((N_NODES + 127) / 128, H_FEATS / 128);
        gemm_kernel<<<gg, 256, 0, stream>>>(Ain, a_fp32, WT, Hbf, nullptr,
                                            avs, avd, asrc, adst,
                                            N_NODES, H_FEATS, Kdim, 1);
        gather_kernel<<<(ndst + 3) / 4, 256, 0, stream>>>(rowptr, srcs, asrc, adst, Hbf, OutBf, ndst, add);
    };

    const void* xa = xbf ? (const void*)xbf : (const void*)x;
    int xa_fp32 = xbf ? 0 : 1;

    // layer 0
    run_conv(xa, xa_fp32, IN_FEATS, WT0a, as0a, ad0a, rowptr1, srcs1, H1, N_NODES, 0);
    run_conv(xa, xa_fp32, IN_FEATS, WT0b, as0b, ad0b, rowptr2, srcs2, H1, N_NODES, 1);
    combine_lrelu_kernel<<<(N_NODES * 64 + 255) / 256, 256, 0, stream>>>(H1, b0a, b0b, N_NODES);

    // layer 1 (only seed dsts needed)
    run_conv(H1, 0, H_FEATS, WT1a, as1a, ad1a, rowptr1, srcs1, Acc2, BATCH, 0);
    run_conv(H1, 0, H_FEATS, WT1b, as1b, ad1b, rowptr2, srcs2, Acc2, BATCH, 1);

    // head
    h2prep_kernel<<<(BATCH * 64 + 255) / 256, 256, 0, stream>>>(Acc2, b1a, b1b, h2s, BATCH);
    dim3 gh(BATCH / 128, (N_CLASSES + 127) / 128);
    gemm_kernel<<<gh, 256, 0, stream>>>(h2s, 0, WTl, out, linb,
                                        nullptr, nullptr, nullptr, nullptr,
                                        BATCH, N_CLASSES, H_FEATS, 0);
}